// Round 1
// 664.185 us; speedup vs baseline: 1.1935x; 1.1935x over previous
//
#include <hip/hip_runtime.h>
#include <math.h>

typedef _Float16 f16;
typedef _Float16 f16x8 __attribute__((ext_vector_type(8)));
typedef _Float16 f16x4 __attribute__((ext_vector_type(4)));
typedef float f32x4 __attribute__((ext_vector_type(4)));

// Problem constants
#define NCLASS   128
#define ED       512        // E = FEAT*EMB
#define NROWS    131072     // N
#define EMBD     64
#define VDIM     32
#define TASKD    64
#define KCLUST   32

// ---- workspace byte layout (fast path): W splits + stats only ----
#define OFF_W0H  0ull
#define OFF_W0L  (OFF_W0H + (size_t)ED*ED*2)
#define OFF_W1H  (OFF_W0L + (size_t)ED*ED*2)
#define OFF_W1L  (OFF_W1H + (size_t)ED*ED*2)
#define OFF_STATS (OFF_W1L + (size_t)ED*ED*2)

// float offsets inside the stats region
#define WS_CNT   0
#define WS_SSUM  128
#define WS_SSQ   (128 + 65536)
#define WS_SIMP  (128 + 2*65536)
#define WS_MEAN  (WS_SIMP + 128)
#define WS_MNORM (WS_MEAN + 65536)
#define WS_NC    (WS_MNORM + 65536)
#define WS_V     (WS_NC + 128)
#define STATS_FLOATS (WS_V + NCLASS*VDIM)
#define WS_NEEDED (OFF_STATS + (size_t)STATS_FLOATS*4)

// =====================================================================
// Prep: split W0/W1 into f16 hi/lo, k-packed layout Wp[((k>>3)*512+n)*8+(k&7)].
// Round 5: coalesced — each thread owns one (kb, n): reads 8 row-strided
// floats (each read is lane-coalesced 256 B) and stores ONE contiguous
// f16x8 per array (fully coalesced 1 KiB/wave) instead of 8 scattered
// 2-B stores.
// =====================================================================
__global__ __launch_bounds__(256) void kPrep(const float* __restrict__ W0,
                                             const float* __restrict__ W1,
                                             f16* __restrict__ w0h, f16* __restrict__ w0l,
                                             f16* __restrict__ w1h, f16* __restrict__ w1l)
{
    const int idx = blockIdx.x * 256 + threadIdx.x;    // 0 .. 2*512*512/8-1
    const int sel = idx >= (ED * ED / 8);
    const float* W = sel ? W1 : W0;
    f16* oh = sel ? w1h : w0h;
    f16* ol = sel ? w1l : w0l;
    const int e8 = idx & (ED * ED / 8 - 1);
    const int n  = e8 & 511;
    const int kb = e8 >> 9;             // 0..63
    f16x8 hv, lv;
    #pragma unroll
    for (int j = 0; j < 8; ++j) {
        const float w = W[(kb * 8 + j) * ED + n];
        const f16 hi = (f16)w;
        hv[j] = hi;
        lv[j] = (f16)(w - (float)hi);
    }
    const int o = (kb * ED + n) * 8;
    *(f16x8*)(oh + o) = hv;
    *(f16x8*)(ol + o) = lv;
}

// =====================================================================
// Fused kernel, round 5: A-operand (x, t) kept as single f16 (weights stay
// exact hi/lo), so:
//   - LDS = one 64x512 f16 tile = 64 KiB  -> 2 blocks/CU (4 waves/SIMD)
//   - 2 MFMAs per tile pair instead of 3  -> 2/3 the matrix work
//   - half the LDS traffic (bank conflicts ~halved)
// XOR-swizzled LDS layout unchanged: Th[row][kb^(row&7)][k&7], row stride
// 512 halfs. B(ks=0) prefetched across each barrier; rest relies on 4-wave
// TLP per SIMD (register double-buffer would not fit the 128-VGPR cap).
// =====================================================================
__global__ __launch_bounds__(512, 4) void kFused(
    const float* __restrict__ x,
    const int*   __restrict__ y,
    const f16*  __restrict__ w0h, const f16* __restrict__ w0l,
    const float* __restrict__ b0,
    const f16*  __restrict__ w1h, const f16* __restrict__ w1l,
    const float* __restrict__ b1,
    float* __restrict__ stats)
{
    __shared__ f16 Th[64 * 512];   // 65,536 B

    const int tid  = threadIdx.x;
    const int lane = tid & 63;
    const int wid  = tid >> 6;          // 0..7 = column group
    const int q    = lane >> 4;         // quad 0..3 -> k-sub-block
    const int ln   = lane & 15;
    const int ncol0 = wid * 64;

    const int cls   = blockIdx.x >> 4;
    const int shot0 = (blockIdx.x & 15) * 64;

#define LOADA(a_, ks_) do {                                               \
    const int pkb_ = (((ks_) * 4 + q) ^ (ln & 7)) * 8;                    \
    _Pragma("unroll")                                                     \
    for (int rt_ = 0; rt_ < 4; ++rt_)                                     \
        a_[rt_] = *(const f16x8*)&Th[(rt_ * 16 + ln) * 512 + pkb_];       \
    } while (0)

#define LOADB(bH_, bL_, wh_, wl_, ks_) do {                               \
    const int kb_ = ((ks_) * 4 + q) * ED + ncol0 + ln;                    \
    _Pragma("unroll")                                                     \
    for (int ct_ = 0; ct_ < 4; ++ct_) {                                   \
        const int bo_ = (kb_ + ct_ * 16) * 8;                             \
        bH_[ct_] = *(const f16x8*)(wh_ + bo_);                            \
        bL_[ct_] = *(const f16x8*)(wl_ + bo_);                            \
    } } while (0)

#define DOMFMA(a_, bH_, bL_) do {                                         \
    _Pragma("unroll")                                                     \
    for (int ct_ = 0; ct_ < 4; ++ct_) {                                   \
        _Pragma("unroll")                                                 \
        for (int rt_ = 0; rt_ < 4; ++rt_) {                               \
            f32x4 c_ = acc[rt_ * 4 + ct_];                                \
            c_ = __builtin_amdgcn_mfma_f32_16x16x32_f16(a_[rt_], bL_[ct_], c_, 0, 0, 0); \
            c_ = __builtin_amdgcn_mfma_f32_16x16x32_f16(a_[rt_], bH_[ct_], c_, 0, 0, 0); \
            acc[rt_ * 4 + ct_] = c_;                                      \
        } } } while (0)

    // ---- phase 0: stage x-tile (64x512) as f16 ----
    #pragma unroll
    for (int i = 0; i < 16; ++i) {
        const int flat = tid + i * 512;         // 0..8191 float4s
        const int row  = flat >> 7;             // 128 float4 per row
        const int f    = flat & 127;
        const long orig = (long)cls + 128L * (shot0 + row);
        const float4 xv = *(const float4*)(x + orig * ED + f * 4);
        f16x4 hv;
        hv[0] = (f16)xv.x; hv[1] = (f16)xv.y;
        hv[2] = (f16)xv.z; hv[3] = (f16)xv.w;
        const int ha = row * 512 + (((f >> 1) ^ (row & 7)) << 3) + ((f & 1) << 2);
        *(f16x4*)&Th[ha] = hv;
    }

    f32x4 acc[16];
    #pragma unroll
    for (int i = 0; i < 16; ++i) acc[i] = (f32x4){0.f, 0.f, 0.f, 0.f};

    f16x8 aH[4], bH[4], bL[4];

    // prefetch B(0) before the barrier (no LDS dependency)
    LOADB(bH, bL, w0h, w0l, 0);
    __syncthreads();

    // ---- phase 1: GEMM1 ----
    #pragma unroll 1
    for (int ks = 0; ks < 16; ++ks) {
        LOADA(aH, ks);
        DOMFMA(aH, bH, bL);
        if (ks < 15) LOADB(bH, bL, w0h, w0l, ks + 1);
    }

    __syncthreads();   // everyone done reading x-tile

    // ---- write t = relu(acc+b0) as f16 back into the same LDS tile ----
    // C/D layout (16x16): m = q*4 + reg, n = lane&15
    #pragma unroll
    for (int ct = 0; ct < 4; ++ct) {
        const int col = ncol0 + ct * 16 + ln;
        const float bv = b0[col];
        const int kbx = col >> 3, ko = col & 7;
        #pragma unroll
        for (int rt = 0; rt < 4; ++rt) {
            #pragma unroll
            for (int rg = 0; rg < 4; ++rg) {
                const int row = rt * 16 + q * 4 + rg;
                const float t = fmaxf(acc[rt * 4 + ct][rg] + bv, 0.f);
                Th[row * 512 + ((kbx ^ (row & 7)) << 3) + ko] = (f16)t;
            }
        }
    }

    #pragma unroll
    for (int i = 0; i < 16; ++i) acc[i] = (f32x4){0.f, 0.f, 0.f, 0.f};

    // prefetch GEMM2 B(0) across the barrier
    LOADB(bH, bL, w1h, w1l, 0);
    __syncthreads();   // t-tile complete

    // ---- phase 2: GEMM2 ----
    #pragma unroll 1
    for (int ks = 0; ks < 16; ++ks) {
        LOADA(aH, ks);
        DOMFMA(aH, bH, bL);
        if (ks < 15) LOADB(bH, bL, w1h, w1l, ks + 1);
    }

    // ---- epilogue: per-class stats (all 64 rows are one class) ----
    const int clsY = y[(long)cls + 128L * shot0];
    float* cnt  = stats + WS_CNT;
    float* ssum = stats + WS_SSUM;
    float* ssq  = stats + WS_SSQ;
    #pragma unroll
    for (int ct = 0; ct < 4; ++ct) {
        const int col = ncol0 + ct * 16 + ln;
        const float bv = b1[col];
        float s = 0.f, qq = 0.f;
        #pragma unroll
        for (int rt = 0; rt < 4; ++rt)
            #pragma unroll
            for (int rg = 0; rg < 4; ++rg) {
                const float h = acc[rt * 4 + ct][rg] + bv;
                s += h; qq += h * h;
            }
        s  += __shfl_xor(s, 16);  qq += __shfl_xor(qq, 16);
        s  += __shfl_xor(s, 32);  qq += __shfl_xor(qq, 32);
        if (lane < 16) {
            atomicAdd(&ssum[clsY * ED + col], s);
            atomicAdd(&ssq [clsY * ED + col], qq);
        }
    }
    if (tid == 0) atomicAdd(&cnt[clsY], 64.0f);

#undef LOADA
#undef LOADB
#undef DOMFMA
}

// =====================================================================
// Round-1 fp32 fallback (used only if ws_size is too small)
// =====================================================================
__device__ __forceinline__ int swz(int k, int r) { return k * 32 + (r ^ (k & 28)); }

__global__ __launch_bounds__(256) void kA(const float* __restrict__ x,
                                          const int* __restrict__ y,
                                          const float* __restrict__ W0,
                                          const float* __restrict__ b0,
                                          const float* __restrict__ W1,
                                          const float* __restrict__ b1,
                                          float* __restrict__ ws)
{
    __shared__ float lds[ED * 32];
    const int tid  = threadIdx.x;
    const int cls  = blockIdx.x & 127;
    const int seg  = blockIdx.x >> 7;
    const int base = seg * 32;
    {
        const int rr = tid >> 7;
        const int k4 = (tid & 127) * 4;
        for (int jj = 0; jj < 16; ++jj) {
            const int r = 2 * jj + rr;
            const long row = (long)cls + 128L * (base + r);
            const float4 xv = *(const float4*)(x + row * ED + k4);
            lds[swz(k4 + 0, r)] = xv.x;
            lds[swz(k4 + 1, r)] = xv.y;
            lds[swz(k4 + 2, r)] = xv.z;
            lds[swz(k4 + 3, r)] = xv.w;
        }
    }
    __syncthreads();
    const int c = tid;
    float acc0[32], acc1[32];
    #pragma unroll
    for (int r = 0; r < 32; ++r) { acc0[r] = 0.f; acc1[r] = 0.f; }
    #pragma unroll 2
    for (int k = 0; k < ED; ++k) {
        const float wa = W0[k * ED + c];
        const float wb = W0[k * ED + c + 256];
        #pragma unroll
        for (int rc = 0; rc < 32; rc += 4) {
            const float4 xv = *(const float4*)&lds[k * 32 + (rc ^ (k & 28))];
            acc0[rc+0] += xv.x * wa; acc1[rc+0] += xv.x * wb;
            acc0[rc+1] += xv.y * wa; acc1[rc+1] += xv.y * wb;
            acc0[rc+2] += xv.z * wa; acc1[rc+2] += xv.z * wb;
            acc0[rc+3] += xv.w * wa; acc1[rc+3] += xv.w * wb;
        }
    }
    const float ba = b0[c], bb = b0[c + 256];
    __syncthreads();
    #pragma unroll
    for (int rc = 0; rc < 32; rc += 4) {
        float4 v0, v1;
        v0.x = fmaxf(acc0[rc+0] + ba, 0.f); v0.y = fmaxf(acc0[rc+1] + ba, 0.f);
        v0.z = fmaxf(acc0[rc+2] + ba, 0.f); v0.w = fmaxf(acc0[rc+3] + ba, 0.f);
        v1.x = fmaxf(acc1[rc+0] + bb, 0.f); v1.y = fmaxf(acc1[rc+1] + bb, 0.f);
        v1.z = fmaxf(acc1[rc+2] + bb, 0.f); v1.w = fmaxf(acc1[rc+3] + bb, 0.f);
        *(float4*)&lds[c * 32 + (rc ^ (c & 28))] = v0;
        *(float4*)&lds[(c + 256) * 32 + (rc ^ (c & 28))] = v1;
    }
    __syncthreads();
    #pragma unroll
    for (int r = 0; r < 32; ++r) { acc0[r] = 0.f; acc1[r] = 0.f; }
    #pragma unroll 2
    for (int k = 0; k < ED; ++k) {
        const float wa = W1[k * ED + c];
        const float wb = W1[k * ED + c + 256];
        #pragma unroll
        for (int rc = 0; rc < 32; rc += 4) {
            const float4 tv = *(const float4*)&lds[k * 32 + (rc ^ (k & 28))];
            acc0[rc+0] += tv.x * wa; acc1[rc+0] += tv.x * wb;
            acc0[rc+1] += tv.y * wa; acc1[rc+1] += tv.y * wb;
            acc0[rc+2] += tv.z * wa; acc1[rc+2] += tv.z * wb;
            acc0[rc+3] += tv.w * wa; acc1[rc+3] += tv.w * wb;
        }
    }
    const float c0 = b1[c], c1 = b1[c + 256];
    #pragma unroll
    for (int r = 0; r < 32; ++r) { acc0[r] += c0; acc1[r] += c1; }
    const int y0 = y[(long)cls + 128L * base];
    bool uni = true;
    #pragma unroll
    for (int r = 1; r < 32; ++r) uni = uni && (y[(long)cls + 128L * (base + r)] == y0);
    float* cnt  = ws + WS_CNT;
    float* ssum = ws + WS_SSUM;
    float* ssq  = ws + WS_SSQ;
    if (uni) {
        float s0 = 0.f, q0 = 0.f, s1 = 0.f, q1 = 0.f;
        #pragma unroll
        for (int r = 0; r < 32; ++r) {
            s0 += acc0[r]; q0 += acc0[r] * acc0[r];
            s1 += acc1[r]; q1 += acc1[r] * acc1[r];
        }
        atomicAdd(&ssum[y0 * ED + c], s0);
        atomicAdd(&ssq [y0 * ED + c], q0);
        atomicAdd(&ssum[y0 * ED + c + 256], s1);
        atomicAdd(&ssq [y0 * ED + c + 256], q1);
        if (tid == 0) atomicAdd(&cnt[y0], 32.0f);
    } else {
        #pragma unroll
        for (int r = 0; r < 32; ++r) {
            const int yr = y[(long)cls + 128L * (base + r)];
            atomicAdd(&ssum[yr * ED + c], acc0[r]);
            atomicAdd(&ssq [yr * ED + c], acc0[r] * acc0[r]);
            atomicAdd(&ssum[yr * ED + c + 256], acc1[r]);
            atomicAdd(&ssq [yr * ED + c + 256], acc1[r] * acc1[r]);
        }
        if (tid == 0)
            for (int r = 0; r < 32; ++r)
                atomicAdd(&cnt[y[(long)cls + 128L * (base + r)]], 1.0f);
    }
}

// ---------------- Stage B1: per-class mean/var/mnorm + s/v MLP ----------------
__global__ __launch_bounds__(256) void kB1(const float* __restrict__ Ws,
                                           const float* __restrict__ bs,
                                           const float* __restrict__ Wv0,
                                           const float* __restrict__ bv0,
                                           const float* __restrict__ Wv1,
                                           const float* __restrict__ bv1,
                                           float* __restrict__ ws)
{
    __shared__ float sv[1025];
    __shared__ float red[256];
    __shared__ float sb[EMBD];
    __shared__ float pb[VDIM];
    const int cI = blockIdx.x, tid = threadIdx.x;
    const float* ssum = ws + WS_SSUM + cI * ED;
    const float* ssq  = ws + WS_SSQ  + cI * ED;
    const float cntv = ws[WS_CNT + cI];

    float nacc = 0.f;
    for (int e = tid; e < ED; e += 256) {
        const float m = ssum[e] / cntv;
        const float qv = ssq[e];
        const float var = (qv - cntv * m * m) / (cntv - 1.0f);
        sv[e] = var;
        sv[512 + e] = m;
        ws[WS_MEAN + cI * ED + e] = m;
        nacc += m * m;
    }
    if (tid == 0) {
        const float Ncv = (cntv - 1.0f) / 1023.0f;
        sv[1024] = Ncv;
        ws[WS_NC + cI] = Ncv;
    }
    red[tid] = nacc;
    __syncthreads();
    for (int off = 128; off > 0; off >>= 1) {
        if (tid < off) red[tid] += red[tid + off];
        __syncthreads();
    }
    const float inv = 1.0f / fmaxf(sqrtf(red[0]), 1e-7f);
    for (int e = tid; e < ED; e += 256)
        ws[WS_MNORM + cI * ED + e] = sv[512 + e] * inv;
    __syncthreads();

    if (tid < EMBD) {
        float a = bs[tid];
        for (int k = 0; k < 1025; ++k) a += sv[k] * Ws[k * EMBD + tid];
        sb[tid] = fmaxf(a, 0.f);
    }
    __syncthreads();
    if (tid < VDIM) {
        float a = bv0[tid];
        for (int k = 0; k < EMBD; ++k) a += sb[k] * Wv0[k * VDIM + tid];
        pb[tid] = fmaxf(a, 0.f);
    }
    __syncthreads();
    if (tid < VDIM) {
        float a = bv1[tid];
        for (int k = 0; k < VDIM; ++k) a += pb[k] * Wv1[k * VDIM + tid];
        ws[WS_V + cI * VDIM + tid] = a;
    }
}

// ---------------- Stage B2: weighted pairwise-cos partial sums ----------------
__global__ __launch_bounds__(128) void kB2(float* __restrict__ ws)
{
    __shared__ float mi[ED];
    __shared__ float red[128];
    const int i = blockIdx.x, tid = threadIdx.x;
    const float* mn = ws + WS_MNORM;
    for (int e = tid; e < ED; e += 128) mi[e] = mn[i * ED + e];
    __syncthreads();
    float contrib = 0.f;
    if (tid > i) {
        const float* rowj = mn + tid * ED;
        float d = 0.f;
        for (int e = 0; e < ED; e += 4) {
            const float4 a = *(const float4*)&mi[e];
            const float4 b = *(const float4*)&rowj[e];
            d += a.x * b.x + a.y * b.y + a.z * b.z + a.w * b.w;
        }
        contrib = (float)(tid - i) * d;
    }
    red[tid] = contrib;
    __syncthreads();
    for (int off = 64; off > 0; off >>= 1) {
        if (tid < off) red[tid] += red[tid + off];
        __syncthreads();
    }
    if (tid == 0) ws[WS_SIMP + i] = red[0];
}

// ---------------- Stage B3: vv -> task -> cluster read-out ----------------
__global__ __launch_bounds__(128) void kB3(const float* __restrict__ W2,
                                           const float* __restrict__ b2,
                                           const float* __restrict__ mem,
                                           float* __restrict__ ws,
                                           float* __restrict__ out)
{
    __shared__ float vv[2 * VDIM + 2];
    __shared__ float task[TASKD];
    __shared__ float Cr[KCLUST];
    __shared__ float rsum;
    const int tid = threadIdx.x;
    const float* v = ws + WS_V;

    if (tid < VDIM) {
        float me = 0.f;
        for (int c = 0; c < NCLASS; ++c) me += v[c * VDIM + tid];
        me /= (float)NCLASS;
        float va = 0.f;
        for (int c = 0; c < NCLASS; ++c) {
            const float d = v[c * VDIM + tid] - me;
            va += d * d;
        }
        va /= (float)(NCLASS - 1);
        vv[tid] = va;
        vv[VDIM + tid] = me;
    }
    if (tid == 32 + VDIM) {
        float a = 0.f;
        for (int c = 0; c < NCLASS; ++c) a += ws[WS_NC + c];
        vv[2 * VDIM] = a / (float)NCLASS;
    }
    if (tid == 33 + VDIM) {
        float a = 0.f;
        for (int i = 0; i < NCLASS; ++i) a += ws[WS_SIMP + i];
        vv[2 * VDIM + 1] = a;
    }
    __syncthreads();
    if (tid < TASKD) {
        float a = b2[tid];
        for (int k = 0; k < 2 * VDIM + 2; ++k) a += vv[k] * W2[k * TASKD + tid];
        task[tid] = fmaxf(a, 0.f);
    }
    __syncthreads();
    if (tid < KCLUST) {
        float dd = 0.f;
        for (int e = 0; e < TASKD; ++e) {
            const float df = task[e] - mem[tid * TASKD + e];
            dd += df * df;
        }
        const float d = sqrtf(dd);
        Cr[tid] = 1.0f / (d + 1.0f);    // TEMP=1: (d+1)^-1
    }
    __syncthreads();
    if (tid == 0) {
        float a = 0.f;
        for (int k = 0; k < KCLUST; ++k) a += Cr[k];
        rsum = a;
    }
    __syncthreads();
    if (tid < TASKD) {
        float a = 0.f;
        for (int k = 0; k < KCLUST; ++k) a += (Cr[k] / rsum) * mem[k * TASKD + tid];
        out[tid] = a;
    }
}

extern "C" void kernel_launch(void* const* d_in, const int* in_sizes, int n_in,
                              void* d_out, int out_size, void* d_ws, size_t ws_size,
                              hipStream_t stream)
{
    const float* x   = (const float*)d_in[0];
    const int*   y   = (const int*)  d_in[1];
    const float* W0  = (const float*)d_in[2];
    const float* b0  = (const float*)d_in[3];
    const float* W1  = (const float*)d_in[4];
    const float* b1  = (const float*)d_in[5];
    const float* Ws  = (const float*)d_in[6];
    const float* bs  = (const float*)d_in[7];
    const float* Wv0 = (const float*)d_in[8];
    const float* bv0 = (const float*)d_in[9];
    const float* Wv1 = (const float*)d_in[10];
    const float* bv1 = (const float*)d_in[11];
    const float* W2  = (const float*)d_in[12];
    const float* b2  = (const float*)d_in[13];
    const float* mem = (const float*)d_in[14];
    float* out = (float*)d_out;

    if (ws_size >= WS_NEEDED) {
        char* wsb = (char*)d_ws;
        f16* w0h = (f16*)(wsb + OFF_W0H);
        f16* w0l = (f16*)(wsb + OFF_W0L);
        f16* w1h = (f16*)(wsb + OFF_W1H);
        f16* w1l = (f16*)(wsb + OFF_W1L);
        float* stats = (float*)(wsb + OFF_STATS);

        hipMemsetAsync(stats, 0, (size_t)WS_SIMP * sizeof(float), stream);
        hipLaunchKernelGGL(kPrep, dim3(2 * ED * ED / 8 / 256), dim3(256), 0, stream,
                           W0, W1, w0h, w0l, w1h, w1l);
        hipLaunchKernelGGL(kFused, dim3(NROWS / 64), dim3(512), 0, stream,
                           x, y, w0h, w0l, b0, w1h, w1l, b1, stats);
        hipLaunchKernelGGL(kB1, dim3(NCLASS), dim3(256), 0, stream, Ws, bs, Wv0, bv0, Wv1, bv1, stats);
        hipLaunchKernelGGL(kB2, dim3(NCLASS), dim3(128), 0, stream, stats);
        hipLaunchKernelGGL(kB3, dim3(1), dim3(128), 0, stream, W2, b2, mem, stats, out);
    } else {
        float* ws = (float*)d_ws;
        hipMemsetAsync(ws, 0, (size_t)WS_SIMP * sizeof(float), stream);
        hipLaunchKernelGGL(kA,  dim3(NROWS / 32), dim3(256), 0, stream, x, y, W0, b0, W1, b1, ws);
        hipLaunchKernelGGL(kB1, dim3(NCLASS), dim3(256), 0, stream, Ws, bs, Wv0, bv0, Wv1, bv1, ws);
        hipLaunchKernelGGL(kB2, dim3(NCLASS), dim3(128), 0, stream, ws);
        hipLaunchKernelGGL(kB3, dim3(1), dim3(128), 0, stream, W2, b2, mem, ws, out);
    }
}

// Round 2
// 524.470 us; speedup vs baseline: 1.5114x; 1.2664x over previous
//
#include <hip/hip_runtime.h>
#include <math.h>

typedef _Float16 f16;
typedef _Float16 f16x8 __attribute__((ext_vector_type(8)));
typedef _Float16 f16x4 __attribute__((ext_vector_type(4)));
typedef float f32x4 __attribute__((ext_vector_type(4)));

// Problem constants
#define NCLASS   128
#define ED       512        // E = FEAT*EMB
#define NROWS    131072     // N
#define EMBD     64
#define VDIM     32
#define TASKD    64
#define KCLUST   32

// ---- workspace byte layout (fast path): f16 weights + stats ----
#define OFF_W0H  0ull
#define OFF_W1H  (OFF_W0H + (size_t)ED*ED*2)
#define OFF_STATS (OFF_W1H + (size_t)ED*ED*2)

// float offsets inside the stats region
#define WS_CNT   0
#define WS_SSUM  128
#define WS_SSQ   (128 + 65536)
#define WS_SIMP  (128 + 2*65536)
#define WS_MEAN  (WS_SIMP + 128)
#define WS_MNORM (WS_MEAN + 65536)
#define WS_NC    (WS_MNORM + 65536)
#define WS_V     (WS_NC + 128)
#define STATS_FLOATS (WS_V + NCLASS*VDIM)
#define WS_NEEDED (OFF_STATS + (size_t)STATS_FLOATS*4)

// =====================================================================
// Prep: convert W0/W1 to f16 (round-to-nearest), k-packed layout
// Wp[((k>>3)*512+n)*8+(k&7)] so a B-fragment (8 consecutive k at fixed n)
// is one contiguous 16-B load. Each thread owns one (kb, n): 8 coalesced
// row-strided float reads -> ONE contiguous f16x8 store.
// =====================================================================
__global__ __launch_bounds__(256) void kPrep(const float* __restrict__ W0,
                                             const float* __restrict__ W1,
                                             f16* __restrict__ w0h,
                                             f16* __restrict__ w1h)
{
    const int idx = blockIdx.x * 256 + threadIdx.x;    // 0 .. 2*512*512/8-1
    const int sel = idx >= (ED * ED / 8);
    const float* W = sel ? W1 : W0;
    f16* oh = sel ? w1h : w0h;
    const int e8 = idx & (ED * ED / 8 - 1);
    const int n  = e8 & 511;
    const int kb = e8 >> 9;             // 0..63
    f16x8 hv;
    #pragma unroll
    for (int j = 0; j < 8; ++j)
        hv[j] = (f16)W[(kb * 8 + j) * ED + n];
    *(f16x8*)(oh + (kb * ED + n) * 8) = hv;
}

// =====================================================================
// Fused kernel, round 6: single-f16 weights -> ONE MFMA per k-tile.
//  - MFMA work halved vs round 5 (floor ~66 us)
//  - B-stream from L2 halved (1 MB/block)
//  - LDS unchanged: one 64x512 f16 tile (64 KiB) -> 2 blocks/CU
//  - explicit B ping-pong (bA/bB), 1 k-step lookahead; A single-buffered
//    (LDS latency short, 4-wave TLP covers the rest)
// XOR-swizzled LDS: Th[row][kb^(row&7)][k&7], row stride 512 halfs.
// =====================================================================
__global__ __launch_bounds__(512, 4) void kFused(
    const float* __restrict__ x,
    const int*   __restrict__ y,
    const f16*  __restrict__ w0h,
    const float* __restrict__ b0,
    const f16*  __restrict__ w1h,
    const float* __restrict__ b1,
    float* __restrict__ stats)
{
    __shared__ f16 Th[64 * 512];   // 65,536 B

    const int tid  = threadIdx.x;
    const int lane = tid & 63;
    const int wid  = tid >> 6;          // 0..7 = column group
    const int q    = lane >> 4;         // quad 0..3 -> k-sub-block
    const int ln   = lane & 15;
    const int ncol0 = wid * 64;

    const int cls   = blockIdx.x >> 4;
    const int shot0 = (blockIdx.x & 15) * 64;

#define LOADA(a_, ks_) do {                                               \
    const int pkb_ = (((ks_) * 4 + q) ^ (ln & 7)) * 8;                    \
    _Pragma("unroll")                                                     \
    for (int rt_ = 0; rt_ < 4; ++rt_)                                     \
        a_[rt_] = *(const f16x8*)&Th[(rt_ * 16 + ln) * 512 + pkb_];       \
    } while (0)

#define LOADB(b_, wp_, ks_) do {                                          \
    const int kb_ = ((ks_) * 4 + q) * ED + ncol0 + ln;                    \
    _Pragma("unroll")                                                     \
    for (int ct_ = 0; ct_ < 4; ++ct_)                                     \
        b_[ct_] = *(const f16x8*)((wp_) + (kb_ + ct_ * 16) * 8);          \
    } while (0)

#define DOMFMA(a_, b_) do {                                               \
    _Pragma("unroll")                                                     \
    for (int ct_ = 0; ct_ < 4; ++ct_) {                                   \
        _Pragma("unroll")                                                 \
        for (int rt_ = 0; rt_ < 4; ++rt_)                                 \
            acc[rt_ * 4 + ct_] = __builtin_amdgcn_mfma_f32_16x16x32_f16(  \
                a_[rt_], b_[ct_], acc[rt_ * 4 + ct_], 0, 0, 0);           \
    } } while (0)

    // ---- phase 0: stage x-tile (64x512) as f16 ----
    #pragma unroll
    for (int i = 0; i < 16; ++i) {
        const int flat = tid + i * 512;         // 0..8191 float4s
        const int row  = flat >> 7;             // 128 float4 per row
        const int f    = flat & 127;
        const long orig = (long)cls + 128L * (shot0 + row);
        const float4 xv = *(const float4*)(x + orig * ED + f * 4);
        f16x4 hv;
        hv[0] = (f16)xv.x; hv[1] = (f16)xv.y;
        hv[2] = (f16)xv.z; hv[3] = (f16)xv.w;
        const int ha = row * 512 + (((f >> 1) ^ (row & 7)) << 3) + ((f & 1) << 2);
        *(f16x4*)&Th[ha] = hv;
    }

    f32x4 acc[16];
    #pragma unroll
    for (int i = 0; i < 16; ++i) acc[i] = (f32x4){0.f, 0.f, 0.f, 0.f};

    f16x8 aH[4], bA[4], bB[4];

    // prefetch B(0) before the barrier (no LDS dependency)
    LOADB(bA, w0h, 0);
    __syncthreads();

    // ---- phase 1: GEMM1 ----
    #pragma unroll 1
    for (int ks = 0; ks < 14; ks += 2) {
        LOADB(bB, w0h, ks + 1);
        LOADA(aH, ks);
        DOMFMA(aH, bA);
        LOADB(bA, w0h, ks + 2);
        LOADA(aH, ks + 1);
        DOMFMA(aH, bB);
    }
    LOADB(bB, w0h, 15);
    LOADA(aH, 14);
    DOMFMA(aH, bA);
    LOADA(aH, 15);
    DOMFMA(aH, bB);

    __syncthreads();   // everyone done reading x-tile

    // ---- write t = relu(acc+b0) as f16 back into the same LDS tile ----
    // C/D layout (16x16): m = q*4 + reg, n = lane&15
    #pragma unroll
    for (int ct = 0; ct < 4; ++ct) {
        const int col = ncol0 + ct * 16 + ln;
        const float bv = b0[col];
        const int kbx = col >> 3, ko = col & 7;
        #pragma unroll
        for (int rt = 0; rt < 4; ++rt) {
            #pragma unroll
            for (int rg = 0; rg < 4; ++rg) {
                const int row = rt * 16 + q * 4 + rg;
                const float t = fmaxf(acc[rt * 4 + ct][rg] + bv, 0.f);
                Th[row * 512 + ((kbx ^ (row & 7)) << 3) + ko] = (f16)t;
            }
        }
    }

    #pragma unroll
    for (int i = 0; i < 16; ++i) acc[i] = (f32x4){0.f, 0.f, 0.f, 0.f};

    // prefetch GEMM2 B(0) across the barrier
    LOADB(bA, w1h, 0);
    __syncthreads();   // t-tile complete

    // ---- phase 2: GEMM2 ----
    #pragma unroll 1
    for (int ks = 0; ks < 14; ks += 2) {
        LOADB(bB, w1h, ks + 1);
        LOADA(aH, ks);
        DOMFMA(aH, bA);
        LOADB(bA, w1h, ks + 2);
        LOADA(aH, ks + 1);
        DOMFMA(aH, bB);
    }
    LOADB(bB, w1h, 15);
    LOADA(aH, 14);
    DOMFMA(aH, bA);
    LOADA(aH, 15);
    DOMFMA(aH, bB);

    // ---- epilogue: per-class stats (all 64 rows are one class) ----
    const int clsY = y[(long)cls + 128L * shot0];
    float* cnt  = stats + WS_CNT;
    float* ssum = stats + WS_SSUM;
    float* ssq  = stats + WS_SSQ;
    #pragma unroll
    for (int ct = 0; ct < 4; ++ct) {
        const int col = ncol0 + ct * 16 + ln;
        const float bv = b1[col];
        float s = 0.f, qq = 0.f;
        #pragma unroll
        for (int rt = 0; rt < 4; ++rt)
            #pragma unroll
            for (int rg = 0; rg < 4; ++rg) {
                const float h = acc[rt * 4 + ct][rg] + bv;
                s += h; qq += h * h;
            }
        s  += __shfl_xor(s, 16);  qq += __shfl_xor(qq, 16);
        s  += __shfl_xor(s, 32);  qq += __shfl_xor(qq, 32);
        if (lane < 16) {
            atomicAdd(&ssum[clsY * ED + col], s);
            atomicAdd(&ssq [clsY * ED + col], qq);
        }
    }
    if (tid == 0) atomicAdd(&cnt[clsY], 64.0f);

#undef LOADA
#undef LOADB
#undef DOMFMA
}

// =====================================================================
// Round-1 fp32 fallback (used only if ws_size is too small)
// =====================================================================
__device__ __forceinline__ int swz(int k, int r) { return k * 32 + (r ^ (k & 28)); }

__global__ __launch_bounds__(256) void kA(const float* __restrict__ x,
                                          const int* __restrict__ y,
                                          const float* __restrict__ W0,
                                          const float* __restrict__ b0,
                                          const float* __restrict__ W1,
                                          const float* __restrict__ b1,
                                          float* __restrict__ ws)
{
    __shared__ float lds[ED * 32];
    const int tid  = threadIdx.x;
    const int cls  = blockIdx.x & 127;
    const int seg  = blockIdx.x >> 7;
    const int base = seg * 32;
    {
        const int rr = tid >> 7;
        const int k4 = (tid & 127) * 4;
        for (int jj = 0; jj < 16; ++jj) {
            const int r = 2 * jj + rr;
            const long row = (long)cls + 128L * (base + r);
            const float4 xv = *(const float4*)(x + row * ED + k4);
            lds[swz(k4 + 0, r)] = xv.x;
            lds[swz(k4 + 1, r)] = xv.y;
            lds[swz(k4 + 2, r)] = xv.z;
            lds[swz(k4 + 3, r)] = xv.w;
        }
    }
    __syncthreads();
    const int c = tid;
    float acc0[32], acc1[32];
    #pragma unroll
    for (int r = 0; r < 32; ++r) { acc0[r] = 0.f; acc1[r] = 0.f; }
    #pragma unroll 2
    for (int k = 0; k < ED; ++k) {
        const float wa = W0[k * ED + c];
        const float wb = W0[k * ED + c + 256];
        #pragma unroll
        for (int rc = 0; rc < 32; rc += 4) {
            const float4 xv = *(const float4*)&lds[k * 32 + (rc ^ (k & 28))];
            acc0[rc+0] += xv.x * wa; acc1[rc+0] += xv.x * wb;
            acc0[rc+1] += xv.y * wa; acc1[rc+1] += xv.y * wb;
            acc0[rc+2] += xv.z * wa; acc1[rc+2] += xv.z * wb;
            acc0[rc+3] += xv.w * wa; acc1[rc+3] += xv.w * wb;
        }
    }
    const float ba = b0[c], bb = b0[c + 256];
    __syncthreads();
    #pragma unroll
    for (int rc = 0; rc < 32; rc += 4) {
        float4 v0, v1;
        v0.x = fmaxf(acc0[rc+0] + ba, 0.f); v0.y = fmaxf(acc0[rc+1] + ba, 0.f);
        v0.z = fmaxf(acc0[rc+2] + ba, 0.f); v0.w = fmaxf(acc0[rc+3] + ba, 0.f);
        v1.x = fmaxf(acc1[rc+0] + bb, 0.f); v1.y = fmaxf(acc1[rc+1] + bb, 0.f);
        v1.z = fmaxf(acc1[rc+2] + bb, 0.f); v1.w = fmaxf(acc1[rc+3] + bb, 0.f);
        *(float4*)&lds[c * 32 + (rc ^ (c & 28))] = v0;
        *(float4*)&lds[(c + 256) * 32 + (rc ^ (c & 28))] = v1;
    }
    __syncthreads();
    #pragma unroll
    for (int r = 0; r < 32; ++r) { acc0[r] = 0.f; acc1[r] = 0.f; }
    #pragma unroll 2
    for (int k = 0; k < ED; ++k) {
        const float wa = W1[k * ED + c];
        const float wb = W1[k * ED + c + 256];
        #pragma unroll
        for (int rc = 0; rc < 32; rc += 4) {
            const float4 tv = *(const float4*)&lds[k * 32 + (rc ^ (k & 28))];
            acc0[rc+0] += tv.x * wa; acc1[rc+0] += tv.x * wb;
            acc0[rc+1] += tv.y * wa; acc1[rc+1] += tv.y * wb;
            acc0[rc+2] += tv.z * wa; acc1[rc+2] += tv.z * wb;
            acc0[rc+3] += tv.w * wa; acc1[rc+3] += tv.w * wb;
        }
    }
    const float c0 = b1[c], c1 = b1[c + 256];
    #pragma unroll
    for (int r = 0; r < 32; ++r) { acc0[r] += c0; acc1[r] += c1; }
    const int y0 = y[(long)cls + 128L * base];
    bool uni = true;
    #pragma unroll
    for (int r = 1; r < 32; ++r) uni = uni && (y[(long)cls + 128L * (base + r)] == y0);
    float* cnt  = ws + WS_CNT;
    float* ssum = ws + WS_SSUM;
    float* ssq  = ws + WS_SSQ;
    if (uni) {
        float s0 = 0.f, q0 = 0.f, s1 = 0.f, q1 = 0.f;
        #pragma unroll
        for (int r = 0; r < 32; ++r) {
            s0 += acc0[r]; q0 += acc0[r] * acc0[r];
            s1 += acc1[r]; q1 += acc1[r] * acc1[r];
        }
        atomicAdd(&ssum[y0 * ED + c], s0);
        atomicAdd(&ssq [y0 * ED + c], q0);
        atomicAdd(&ssum[y0 * ED + c + 256], s1);
        atomicAdd(&ssq [y0 * ED + c + 256], q1);
        if (tid == 0) atomicAdd(&cnt[y0], 32.0f);
    } else {
        #pragma unroll
        for (int r = 0; r < 32; ++r) {
            const int yr = y[(long)cls + 128L * (base + r)];
            atomicAdd(&ssum[yr * ED + c], acc0[r]);
            atomicAdd(&ssq [yr * ED + c], acc0[r] * acc0[r]);
            atomicAdd(&ssum[yr * ED + c + 256], acc1[r]);
            atomicAdd(&ssq [yr * ED + c + 256], acc1[r] * acc1[r]);
        }
        if (tid == 0)
            for (int r = 0; r < 32; ++r)
                atomicAdd(&cnt[y[(long)cls + 128L * (base + r)]], 1.0f);
    }
}

// ---------------- Stage B1: per-class mean/var/mnorm + s/v MLP ----------------
__global__ __launch_bounds__(256) void kB1(const float* __restrict__ Ws,
                                           const float* __restrict__ bs,
                                           const float* __restrict__ Wv0,
                                           const float* __restrict__ bv0,
                                           const float* __restrict__ Wv1,
                                           const float* __restrict__ bv1,
                                           float* __restrict__ ws)
{
    __shared__ float sv[1025];
    __shared__ float red[256];
    __shared__ float sb[EMBD];
    __shared__ float pb[VDIM];
    const int cI = blockIdx.x, tid = threadIdx.x;
    const float* ssum = ws + WS_SSUM + cI * ED;
    const float* ssq  = ws + WS_SSQ  + cI * ED;
    const float cntv = ws[WS_CNT + cI];

    float nacc = 0.f;
    for (int e = tid; e < ED; e += 256) {
        const float m = ssum[e] / cntv;
        const float qv = ssq[e];
        const float var = (qv - cntv * m * m) / (cntv - 1.0f);
        sv[e] = var;
        sv[512 + e] = m;
        ws[WS_MEAN + cI * ED + e] = m;
        nacc += m * m;
    }
    if (tid == 0) {
        const float Ncv = (cntv - 1.0f) / 1023.0f;
        sv[1024] = Ncv;
        ws[WS_NC + cI] = Ncv;
    }
    red[tid] = nacc;
    __syncthreads();
    for (int off = 128; off > 0; off >>= 1) {
        if (tid < off) red[tid] += red[tid + off];
        __syncthreads();
    }
    const float inv = 1.0f / fmaxf(sqrtf(red[0]), 1e-7f);
    for (int e = tid; e < ED; e += 256)
        ws[WS_MNORM + cI * ED + e] = sv[512 + e] * inv;
    __syncthreads();

    // s = relu(sv @ Ws + bs): 256 threads = 64 outputs x 4 k-slices
    {
        const int o  = tid & 63;
        const int sl = tid >> 6;
        const int k0 = sl * 256;
        float a = 0.f;
        for (int k = k0; k < k0 + 256; ++k) a += sv[k] * Ws[k * EMBD + o];
        if (sl == 3) a += sv[1024] * Ws[1024 * EMBD + o];
        red[tid] = a;
    }
    __syncthreads();
    if (tid < EMBD) {
        const float a = red[tid] + red[tid + 64] + red[tid + 128] + red[tid + 192] + bs[tid];
        sb[tid] = fmaxf(a, 0.f);
    }
    __syncthreads();
    if (tid < VDIM) {
        float a = bv0[tid];
        for (int k = 0; k < EMBD; ++k) a += sb[k] * Wv0[k * VDIM + tid];
        pb[tid] = fmaxf(a, 0.f);
    }
    __syncthreads();
    if (tid < VDIM) {
        float a = bv1[tid];
        for (int k = 0; k < VDIM; ++k) a += pb[k] * Wv1[k * VDIM + tid];
        ws[WS_V + cI * VDIM + tid] = a;
    }
}

// ---------------- Stage B2: weighted pairwise-cos partial sums ----------------
__global__ __launch_bounds__(128) void kB2(float* __restrict__ ws)
{
    __shared__ float mi[ED];
    __shared__ float red[128];
    const int i = blockIdx.x, tid = threadIdx.x;
    const float* mn = ws + WS_MNORM;
    for (int e = tid; e < ED; e += 128) mi[e] = mn[i * ED + e];
    __syncthreads();
    float contrib = 0.f;
    if (tid > i) {
        const float* rowj = mn + tid * ED;
        float d = 0.f;
        for (int e = 0; e < ED; e += 4) {
            const float4 a = *(const float4*)&mi[e];
            const float4 b = *(const float4*)&rowj[e];
            d += a.x * b.x + a.y * b.y + a.z * b.z + a.w * b.w;
        }
        contrib = (float)(tid - i) * d;
    }
    red[tid] = contrib;
    __syncthreads();
    for (int off = 64; off > 0; off >>= 1) {
        if (tid < off) red[tid] += red[tid + off];
        __syncthreads();
    }
    if (tid == 0) ws[WS_SIMP + i] = red[0];
}

// ---------------- Stage B3: vv -> task -> cluster read-out ----------------
__global__ __launch_bounds__(128) void kB3(const float* __restrict__ W2,
                                           const float* __restrict__ b2,
                                           const float* __restrict__ mem,
                                           float* __restrict__ ws,
                                           float* __restrict__ out)
{
    __shared__ float vv[2 * VDIM + 2];
    __shared__ float task[TASKD];
    __shared__ float Cr[KCLUST];
    __shared__ float rsum;
    const int tid = threadIdx.x;
    const float* v = ws + WS_V;

    if (tid < VDIM) {
        float me = 0.f;
        for (int c = 0; c < NCLASS; ++c) me += v[c * VDIM + tid];
        me /= (float)NCLASS;
        float va = 0.f;
        for (int c = 0; c < NCLASS; ++c) {
            const float d = v[c * VDIM + tid] - me;
            va += d * d;
        }
        va /= (float)(NCLASS - 1);
        vv[tid] = va;
        vv[VDIM + tid] = me;
    }
    if (tid == 32 + VDIM) {
        float a = 0.f;
        for (int c = 0; c < NCLASS; ++c) a += ws[WS_NC + c];
        vv[2 * VDIM] = a / (float)NCLASS;
    }
    if (tid == 33 + VDIM) {
        float a = 0.f;
        for (int i = 0; i < NCLASS; ++i) a += ws[WS_SIMP + i];
        vv[2 * VDIM + 1] = a;
    }
    __syncthreads();
    if (tid < TASKD) {
        float a = b2[tid];
        for (int k = 0; k < 2 * VDIM + 2; ++k) a += vv[k] * W2[k * TASKD + tid];
        task[tid] = fmaxf(a, 0.f);
    }
    __syncthreads();
    if (tid < KCLUST) {
        float dd = 0.f;
        for (int e = 0; e < TASKD; ++e) {
            const float df = task[e] - mem[tid * TASKD + e];
            dd += df * df;
        }
        const float d = sqrtf(dd);
        Cr[tid] = 1.0f / (d + 1.0f);    // TEMP=1: (d+1)^-1
    }
    __syncthreads();
    if (tid == 0) {
        float a = 0.f;
        for (int k = 0; k < KCLUST; ++k) a += Cr[k];
        rsum = a;
    }
    __syncthreads();
    if (tid < TASKD) {
        float a = 0.f;
        for (int k = 0; k < KCLUST; ++k) a += (Cr[k] / rsum) * mem[k * TASKD + tid];
        out[tid] = a;
    }
}

extern "C" void kernel_launch(void* const* d_in, const int* in_sizes, int n_in,
                              void* d_out, int out_size, void* d_ws, size_t ws_size,
                              hipStream_t stream)
{
    const float* x   = (const float*)d_in[0];
    const int*   y   = (const int*)  d_in[1];
    const float* W0  = (const float*)d_in[2];
    const float* b0  = (const float*)d_in[3];
    const float* W1  = (const float*)d_in[4];
    const float* b1  = (const float*)d_in[5];
    const float* Ws  = (const float*)d_in[6];
    const float* bs  = (const float*)d_in[7];
    const float* Wv0 = (const float*)d_in[8];
    const float* bv0 = (const float*)d_in[9];
    const float* Wv1 = (const float*)d_in[10];
    const float* bv1 = (const float*)d_in[11];
    const float* W2  = (const float*)d_in[12];
    const float* b2  = (const float*)d_in[13];
    const float* mem = (const float*)d_in[14];
    float* out = (float*)d_out;

    if (ws_size >= WS_NEEDED) {
        char* wsb = (char*)d_ws;
        f16* w0h = (f16*)(wsb + OFF_W0H);
        f16* w1h = (f16*)(wsb + OFF_W1H);
        float* stats = (float*)(wsb + OFF_STATS);

        hipMemsetAsync(stats, 0, (size_t)WS_SIMP * sizeof(float), stream);
        hipLaunchKernelGGL(kPrep, dim3(2 * ED * ED / 8 / 256), dim3(256), 0, stream,
                           W0, W1, w0h, w1h);
        hipLaunchKernelGGL(kFused, dim3(NROWS / 64), dim3(512), 0, stream,
                           x, y, w0h, b0, w1h, b1, stats);
        hipLaunchKernelGGL(kB1, dim3(NCLASS), dim3(256), 0, stream, Ws, bs, Wv0, bv0, Wv1, bv1, stats);
        hipLaunchKernelGGL(kB2, dim3(NCLASS), dim3(128), 0, stream, stats);
        hipLaunchKernelGGL(kB3, dim3(1), dim3(128), 0, stream, W2, b2, mem, stats, out);
    } else {
        float* ws = (float*)d_ws;
        hipMemsetAsync(ws, 0, (size_t)WS_SIMP * sizeof(float), stream);
        hipLaunchKernelGGL(kA,  dim3(NROWS / 32), dim3(256), 0, stream, x, y, W0, b0, W1, b1, ws);
        hipLaunchKernelGGL(kB1, dim3(NCLASS), dim3(256), 0, stream, Ws, bs, Wv0, bv0, Wv1, bv1, ws);
        hipLaunchKernelGGL(kB2, dim3(NCLASS), dim3(128), 0, stream, ws);
        hipLaunchKernelGGL(kB3, dim3(1), dim3(128), 0, stream, W2, b2, mem, ws, out);
    }
}